// Round 15
// baseline (1528.645 us; speedup 1.0000x reference)
//
#include <hip/hip_runtime.h>
#include <math.h>

#define B_    16
#define H_    16
#define N_    4096
#define T_    8
#define DS_   256
#define DID_  128
#define L_    8
#define K_    32
#define DHID_ 1024
#define DSTEER_ 896
#define QH_   512
#define QO_   256
#define NW_   256   // B*H walkers
#define SLOTS_ 512  // chunk-slot space: 16 chunks x 32 slots
#define BSLD_ 36    // LDS B-tile row pad (conflict-free b128 reads)
#define SCORE_SCALE 0.022097086912079608f  // 1/(8*sqrt(32))

struct KArgs {
    const float *s_in, *node_id, *ws_in, *token, *norm_w;
    const float *W1, *b1, *W2, *b2;
    const float *qw1, *qb1, *qw2, *qb2, *kw1, *kb1, *kw2, *kb2;
    const int *walker_pos, *plane_idx, *neighbors;
    float *out_motor, *out_s, *out_pos, *out_ws, *out_co, *out_vc, *out_lb;
    float *keys, *kh, *qw1T, *qw2T, *h1p, *q1p, *c2p, *q2p, *mp_all;
    int *pos, *plane_order, *chunk_plane, *chunk_rows, *slot_of, *nchunks, *done;
};

__device__ __forceinline__ float gelu_exact(float x) {
    return 0.5f * x * (1.0f + erff(x * 0.70710678118654752f));
}

#define FMA4(c, b, a) { c.x = fmaf(b.x, (a), c.x); c.y = fmaf(b.y, (a), c.y); \
                        c.z = fmaf(b.z, (a), c.z); c.w = fmaf(b.w, (a), c.w); }

__device__ __forceinline__ void gelu4(float4& v) {
    v.x = gelu_exact(v.x); v.y = gelu_exact(v.y);
    v.z = gelu_exact(v.z); v.w = gelu_exact(v.w);
}

// 2-row x 4-col register tile; A from global, B in LDS (row stride ldb).
__device__ __forceinline__ void rgemm_inner(
    const float* __restrict__ a0, const float* __restrict__ a1,
    const float* bp, int ldb, int K,
    float4& c0, float4& c1)
{
    for (int k = 0; k < K; k += 8) {
        const float4 a0l = *reinterpret_cast<const float4*>(a0 + k);
        const float4 a0h = *reinterpret_cast<const float4*>(a0 + k + 4);
        const float4 a1l = *reinterpret_cast<const float4*>(a1 + k);
        const float4 a1h = *reinterpret_cast<const float4*>(a1 + k + 4);
        const float* b8 = bp + (size_t)k * ldb;
#define KSTEP(o, av0, av1) { float4 bv = *reinterpret_cast<const float4*>(b8 + (size_t)(o) * ldb); \
                             FMA4(c0, bv, av0); FMA4(c1, bv, av1); }
        KSTEP(0, a0l.x, a1l.x)
        KSTEP(1, a0l.y, a1l.y)
        KSTEP(2, a0l.z, a1l.z)
        KSTEP(3, a0l.w, a1l.w)
        KSTEP(4, a0h.x, a1h.x)
        KSTEP(5, a0h.y, a1h.y)
        KSTEP(6, a0h.z, a1h.z)
        KSTEP(7, a0h.w, a1h.w)
#undef KSTEP
    }
}

// ---- setup1: keysA (0..1023) + tables (1024) + qw1T/qw2T transpose
//      (1025..1600) + s/ws copy (1601..3648) --------------------------------

__global__ __launch_bounds__(256) void setup1_kernel(KArgs a)
{
    int bid = blockIdx.x, tid = threadIdx.x;
    if (bid < 1024) {
        // keysA: kh = gelu(node_id @ kw1 + kb1)
        int u = bid;
        int rt = u >> 3, ct = u & 7;
        int tr = tid >> 4, tc = tid & 15;
        int row = rt * 32 + tr * 2, col = ct * 64 + tc * 4;
        const float* a0 = a.node_id + (size_t)row * DID_;
        float4 c0 = {0.f,0.f,0.f,0.f}, c1 = {0.f,0.f,0.f,0.f};
        rgemm_inner(a0, a0 + DID_, a.kw1 + col, QH_, DID_, c0, c1);
        float4 bv = *reinterpret_cast<const float4*>(a.kb1 + col);
        c0.x += bv.x; c0.y += bv.y; c0.z += bv.z; c0.w += bv.w;
        c1.x += bv.x; c1.y += bv.y; c1.z += bv.z; c1.w += bv.w;
        gelu4(c0); gelu4(c1);
        *reinterpret_cast<float4*>(a.kh + (size_t)row * QH_ + col) = c0;
        *reinterpret_cast<float4*>(a.kh + (size_t)(row + 1) * QH_ + col) = c1;
    } else if (bid == 1024) {
        a.pos[tid] = a.walker_pos[tid];
        a.mp_all[tid] = 0.f;
        if (tid < 8) a.done[tid] = 0;
        __shared__ int cnt_s[8];
        __shared__ int cplane_s[16], cbase_s[16];
        __shared__ int nch_s;
        int wave = tid >> 6, lane = tid & 63;
        for (int pp = wave; pp < 8; pp += 4) {
            int base = 0;
            for (int c0 = 0; c0 < NW_; c0 += 64) {
                int w = c0 + lane;
                bool hit = (a.plane_idx[w] == pp);
                unsigned long long mask = __ballot(hit);
                if (hit) {
                    int rank = __popcll(mask & ((1ull << lane) - 1ull));
                    a.plane_order[pp * NW_ + base + rank] = w;
                }
                base += __popcll(mask);
            }
            if (lane == 0) cnt_s[pp] = base;
        }
        __syncthreads();
        if (tid == 0) {
            int nc = 0;
            for (int p = 0; p < 8; ++p)
                for (int s0 = 0; s0 < cnt_s[p]; s0 += 32) {
                    cplane_s[nc] = p; cbase_s[nc] = s0; ++nc;
                }
            *a.nchunks = nc;
            nch_s = nc;
        }
        __syncthreads();
        int nc = nch_s;
        for (int idx = tid; idx < 512; idx += 256) {
            int c = idx >> 5, i = idx & 31;
            int v = -1;
            if (c < nc) {
                int p = cplane_s[c];
                int r = cbase_s[c] + i;
                if (r < cnt_s[p]) v = a.plane_order[p * NW_ + r];
            }
            a.chunk_rows[c * 32 + i] = v;
            if (v >= 0) a.slot_of[v] = c * 32 + i;
            if (i == 0) a.chunk_plane[c] = (c < nc) ? cplane_s[c] : 0;
        }
    } else if (bid < 1601) {
        // weight transposes via 32x32 LDS tiles
        __shared__ float ts[32][33];
        int u = bid - 1025;
        const float* src; float* dst; int srcld, dstld, td, tj;
        if (u < 448) {              // qw1 [896][512] -> qw1T [512][896]
            src = a.qw1; dst = a.qw1T; srcld = QH_; dstld = DSTEER_;
            td = u >> 4; tj = u & 15;
        } else {                    // qw2 [512][256] -> qw2T [256][512]
            u -= 448;               // 128 blocks
            src = a.qw2; dst = a.qw2T; srcld = QO_; dstld = QH_;
            td = u >> 3; tj = u & 7;
        }
#pragma unroll
        for (int i = 0; i < 4; ++i) {
            int e = tid + i * 256;
            int r = e >> 5, cc = e & 31;
            ts[r][cc] = src[(size_t)(td * 32 + r) * srcld + tj * 32 + cc];
        }
        __syncthreads();
#pragma unroll
        for (int i = 0; i < 4; ++i) {
            int e = tid + i * 256;
            int r = e >> 5, cc = e & 31;
            dst[(size_t)(tj * 32 + r) * dstld + td * 32 + cc] = ts[cc][r];
        }
    } else {
        // s / ws restore copy
        int gid = (bid - 1601) * 256 + tid, stride = 2048 * 256;
        float4* s4o = reinterpret_cast<float4*>(a.out_s);
        const float4* s4i = reinterpret_cast<const float4*>(a.s_in);
        for (int i = gid; i < 4194304; i += stride) s4o[i] = s4i[i];
        float4* w4o = reinterpret_cast<float4*>(a.out_ws);
        const float4* w4i = reinterpret_cast<const float4*>(a.ws_in);
        for (int i = gid; i < 16384; i += stride) w4o[i] = w4i[i];
    }
}

// ---------------- setup2: keysB (512 blocks) ----------------

__global__ __launch_bounds__(256) void setup2_kernel(KArgs a)
{
    int bid = blockIdx.x, tid = threadIdx.x;
    int rt = bid >> 2, ct = bid & 3;
    int tr = tid >> 4, tc = tid & 15;
    int row = rt * 32 + tr * 2, col = ct * 64 + tc * 4;
    const float* a0 = a.kh + (size_t)row * QH_;
    float4 c0 = {0.f,0.f,0.f,0.f}, c1 = {0.f,0.f,0.f,0.f};
    rgemm_inner(a0, a0 + QH_, a.kw2 + col, QO_, QH_, c0, c1);
    float4 bv = *reinterpret_cast<const float4*>(a.kb2 + col);
    c0.x += bv.x; c0.y += bv.y; c0.z += bv.z; c0.w += bv.w;
    c1.x += bv.x; c1.y += bv.y; c1.z += bv.z; c1.w += bv.w;
    *reinterpret_cast<float4*>(a.keys + (size_t)row * QO_ + col) = c0;
    *reinterpret_cast<float4*>(a.keys + (size_t)(row + 1) * QO_ + col) = c1;
}

// ---------------- layer1 with fused steer staging (r14 proven) ----------------

__global__ __launch_bounds__(256) void l1_kernel(KArgs a, int t)
{
    __shared__ float bs[224 * BSLD_];        // 32.25 KB
    __shared__ float rms_s[32];
    __shared__ int w_s[32], pos_s[32];
    int bid = blockIdx.x, tid = threadIdx.x;
    int kp, jt, c = -1, p = 0, wt = 0, isQ;
    if (bid < 256) {
        isQ = 1; kp = bid & 3;
        int tile = bid >> 2;                 // 64: wt(8) x jt(8)
        wt = tile >> 3; jt = tile & 7;
    } else {
        isQ = 0;
        int b2 = bid - 256; kp = b2 & 3;
        int tile = b2 >> 2;                  // 256: c(16) x jt(16)
        c = tile >> 4; jt = tile & 15;
        if (c >= *a.nchunks) return;
        p = a.chunk_plane[c];
    }
    int g = tid >> 3, l8 = tid & 7;          // g: walker column, l8: k-chunk
    if (l8 == 0) {
        int w = isQ ? (wt * 32 + g) : a.chunk_rows[c * 32 + g];
        w_s[g] = w;
        pos_s[g] = (w >= 0) ? a.pos[w] : 0;
    }
    __syncthreads();
    if (kp < 2) {                            // rms only needed when slice hits s_n
        int w = w_s[g];
        float ssum = 0.f;
        if (w >= 0) {
            const float* sr = a.out_s + ((size_t)(w >> 4) * N_ + pos_s[g]) * DS_ + l8 * 32;
#pragma unroll
            for (int i = 0; i < 8; ++i) {
                float4 v = *reinterpret_cast<const float4*>(sr + i * 4);
                ssum += v.x * v.x + v.y * v.y + v.z * v.z + v.w * v.w;
            }
        }
        ssum += __shfl_xor(ssum, 1);
        ssum += __shfl_xor(ssum, 2);
        ssum += __shfl_xor(ssum, 4);
        if (l8 == 0) rms_s[g] = rsqrtf(ssum * (1.0f / DS_) + 1e-6f);
    }
    __syncthreads();
    {   // stage B: column g, elems kk = l8*28 .. +28
        int w = w_s[g];
        int b = (w >= 0) ? (w >> 4) : 0;
        int pp = pos_s[g];
        float rr = (kp < 2) ? rms_s[g] : 0.f;
#pragma unroll
        for (int i = 0; i < 7; ++i) {
            int kk = l8 * 28 + i * 4;
            int d4 = kp * 224 + kk;
            float4 v = make_float4(0.f, 0.f, 0.f, 0.f);
            if (w >= 0) {
                if (d4 < 256) {
                    float4 sv = *reinterpret_cast<const float4*>(
                        a.out_s + ((size_t)b * N_ + pp) * DS_ + d4);
                    float4 nv = *reinterpret_cast<const float4*>(a.norm_w + d4);
                    v.x = sv.x * rr * nv.x; v.y = sv.y * rr * nv.y;
                    v.z = sv.z * rr * nv.z; v.w = sv.w * rr * nv.w;
                } else if (d4 < 384) {
                    v = *reinterpret_cast<const float4*>(
                        a.node_id + (size_t)pp * DID_ + (d4 - 256));
                } else if (d4 < 640) {
                    v = *reinterpret_cast<const float4*>(
                        a.out_ws + (size_t)w * DS_ + (d4 - 384));
                } else {
                    v = *reinterpret_cast<const float4*>(
                        a.token + ((size_t)b * T_ + t) * DS_ + (d4 - 640));
                }
            }
            bs[(kk + 0) * BSLD_ + g] = v.x;
            bs[(kk + 1) * BSLD_ + g] = v.y;
            bs[(kk + 2) * BSLD_ + g] = v.z;
            bs[(kk + 3) * BSLD_ + g] = v.w;
        }
    }
    __syncthreads();
    int tr = tid >> 3, tc = tid & 7;
    float4 c0 = {0.f,0.f,0.f,0.f}, c1 = {0.f,0.f,0.f,0.f};
    if (isQ) {
        int j = jt * 64 + tr * 2;
        const float* a0 = a.qw1T + (size_t)j * DSTEER_ + kp * 224;
        rgemm_inner(a0, a0 + DSTEER_, bs + tc * 4, BSLD_, 224, c0, c1);
        float* o = a.q1p + (size_t)kp * 131072;  // [512 j][256 w]
        int w4 = wt * 32 + tc * 4;
        *reinterpret_cast<float4*>(o + (size_t)j * NW_ + w4) = c0;
        *reinterpret_cast<float4*>(o + (size_t)(j + 1) * NW_ + w4) = c1;
    } else {
        int J = jt * 64 + tr * 2;
        const float* a0 = a.W1 + ((size_t)p * DHID_ + J) * DSTEER_ + kp * 224;
        rgemm_inner(a0, a0 + DSTEER_, bs + tc * 4, BSLD_, 224, c0, c1);
        float* o = a.h1p + (size_t)kp * 524288;  // [1024 J][512 slots]
        int slot = c * 32 + tc * 4;
        *reinterpret_cast<float4*>(o + (size_t)J * SLOTS_ + slot) = c0;
        *reinterpret_cast<float4*>(o + (size_t)(J + 1) * SLOTS_ + slot) = c1;
    }
}

// ---------------- l2f + score fused via done-counter ----------------
// blocks 0..255:   q out producers (as r14)
// blocks 256..767: content out producers (as r14)
// blocks 768..1023: score consumers — spin on done[t]==768, then score walker.

__global__ __launch_bounds__(256) void l2fs_kernel(KArgs a, int t)
{
    __shared__ float smem[4224];             // 16.5 KB (producers)
    int bid = blockIdx.x, tid = threadIdx.x;
    if (bid < 256) {
        int kp = bid & 7, tile = bid >> 3;   // 32: colt(4) x wt(8)
        int colt = tile >> 3, wt = tile & 7;
#pragma unroll
        for (int i = 0; i < 8; ++i) {
            int idx = tid + i * 256;         // 2048
            int hh = idx >> 5, wl = idx & 31;
            size_t off = (size_t)(kp * 64 + hh) * NW_ + wt * 32 + wl;
            float acc = a.qb1[kp * 64 + hh];
#pragma unroll
            for (int p4 = 0; p4 < 4; ++p4) acc += a.q1p[(size_t)p4 * 131072 + off];
            smem[hh * 32 + wl] = gelu_exact(acc);
        }
        __syncthreads();
        int tr = tid >> 3, tc = tid & 7;
        int col = colt * 64 + tr * 2;
        const float* a0 = a.qw2T + (size_t)col * QH_ + kp * 64;
        float4 c0 = {0.f,0.f,0.f,0.f}, c1 = {0.f,0.f,0.f,0.f};
        rgemm_inner(a0, a0 + QH_, smem + tc * 4, 32, 64, c0, c1);
        __syncthreads();
        int cl = tr * 2;
        smem[(tc*4+0)*66 + cl]     = c0.x;
        smem[(tc*4+1)*66 + cl]     = c0.y;
        smem[(tc*4+2)*66 + cl]     = c0.z;
        smem[(tc*4+3)*66 + cl]     = c0.w;
        smem[(tc*4+0)*66 + cl + 1] = c1.x;
        smem[(tc*4+1)*66 + cl + 1] = c1.y;
        smem[(tc*4+2)*66 + cl + 1] = c1.z;
        smem[(tc*4+3)*66 + cl + 1] = c1.w;
        __syncthreads();
        float* o = a.q2p + (size_t)kp * 65536;   // [256 w][256 col]
#pragma unroll
        for (int i = 0; i < 2; ++i) {
            int f4i = tid + i * 256;
            int wl = f4i >> 4, j4 = (f4i & 15) << 2;
            float4 v;
            v.x = smem[wl * 66 + j4 + 0];
            v.y = smem[wl * 66 + j4 + 1];
            v.z = smem[wl * 66 + j4 + 2];
            v.w = smem[wl * 66 + j4 + 3];
            *reinterpret_cast<float4*>(o + (size_t)(wt * 32 + wl) * QO_ + colt * 64 + j4) = v;
        }
        __syncthreads();
        __threadfence();
        if (tid == 0) atomicAdd(&a.done[t], 1);
    } else if (bid < 768) {
        int b2i = bid - 256;
        int kp = b2i & 7, tile = b2i >> 3;
        int c = tile >> 2, jt = tile & 3;
        if (c < *a.nchunks) {
            int p = a.chunk_plane[c];
            int tr = tid >> 3, tc = tid & 7;
            int J = jt * 64 + tr * 2;
            float4 c0 = {0.f,0.f,0.f,0.f}, c1 = {0.f,0.f,0.f,0.f};
#pragma unroll
            for (int i = 0; i < 4; ++i) {
                int idx = tid + i * 256;         // 1024
                int kk = idx >> 3, s4 = (idx & 7) << 2;
                int kq = kp * 128 + kk;
                size_t off = (size_t)kq * SLOTS_ + c * 32 + s4;
                float bj = a.b1[p * DHID_ + kq];
                float4 acc = {bj, bj, bj, bj};
#pragma unroll
                for (int p4 = 0; p4 < 4; ++p4) {
                    float4 v = *reinterpret_cast<const float4*>(a.h1p + (size_t)p4 * 524288 + off);
                    acc.x += v.x; acc.y += v.y; acc.z += v.z; acc.w += v.w;
                }
                gelu4(acc);
                *reinterpret_cast<float4*>(smem + kk * 32 + s4) = acc;
            }
            __syncthreads();
            const float* a0 = a.W2 + ((size_t)p * DS_ + J) * DHID_ + kp * 128;
            rgemm_inner(a0, a0 + DHID_, smem + tc * 4, 32, 128, c0, c1);
            __syncthreads();
            int jl = tr * 2;
            smem[(tc*4+0)*66 + jl]     = c0.x;
            smem[(tc*4+1)*66 + jl]     = c0.y;
            smem[(tc*4+2)*66 + jl]     = c0.z;
            smem[(tc*4+3)*66 + jl]     = c0.w;
            smem[(tc*4+0)*66 + jl + 1] = c1.x;
            smem[(tc*4+1)*66 + jl + 1] = c1.y;
            smem[(tc*4+2)*66 + jl + 1] = c1.z;
            smem[(tc*4+3)*66 + jl + 1] = c1.w;
            __syncthreads();
            float* o = a.c2p + (size_t)kp * 131072;  // [512 slot][256 J]
#pragma unroll
            for (int i = 0; i < 2; ++i) {
                int f4i = tid + i * 256;
                int sl = f4i >> 4, j4 = (f4i & 15) << 2;
                float4 v;
                v.x = smem[sl * 66 + j4 + 0];
                v.y = smem[sl * 66 + j4 + 1];
                v.z = smem[sl * 66 + j4 + 2];
                v.w = smem[sl * 66 + j4 + 3];
                *reinterpret_cast<float4*>(o + (size_t)(c * 32 + sl) * 256 + jt * 64 + j4) = v;
            }
            __syncthreads();
        }
        __threadfence();
        if (tid == 0) atomicAdd(&a.done[t], 1);
    } else {
        // ---- score consumer for walker w ----
        int w = bid - 768;
        int b = w >> 4;
        __shared__ float qv_s[256];
        __shared__ int nbr_s[32];
        __shared__ float part_s[8][32];
        __shared__ float sc_s[32];
        int pold = a.pos[w];
        int slot = a.slot_of[w];
        if (tid == 0) {
            while (atomicAdd(&a.done[t], 0) < 768) __builtin_amdgcn_s_sleep(8);
        }
        __syncthreads();
        __threadfence();     // acquire: see producers' q2p/c2p writes
        if (tid < 32) nbr_s[tid] = a.neighbors[(size_t)pold * K_ + tid];
        float qsum = a.qb2[tid];
#pragma unroll
        for (int kp = 0; kp < 8; ++kp) qsum += a.q2p[(size_t)kp * 65536 + (size_t)w * QO_ + tid];
        qv_s[tid] = qsum;
        float csum = a.b2[a.chunk_plane[slot >> 5] * DS_ + tid];
#pragma unroll
        for (int kp = 0; kp < 8; ++kp) csum += a.c2p[(size_t)kp * 131072 + (size_t)slot * 256 + tid];
        __syncthreads();
        int k = tid & 31, part = tid >> 5;
        int nk = nbr_s[k];
        const float* kp_ = a.keys + (size_t)nk * 256 + part * 32;
        const float* qp = qv_s + part * 32;
        float acc = 0.f;
#pragma unroll
        for (int i = 0; i < 32; i += 4) {
            float4 kv = *reinterpret_cast<const float4*>(kp_ + i);
            acc += kv.x * qp[i] + kv.y * qp[i+1] + kv.z * qp[i+2] + kv.w * qp[i+3];
        }
        part_s[part][k] = acc;
        __syncthreads();
        if (tid < 32) {
            float s = 0.f;
#pragma unroll
            for (int p8 = 0; p8 < 8; ++p8) s += part_s[p8][tid];
            sc_s[tid] = s * SCORE_SCALE;
        }
        __syncthreads();
        if (tid < 32) {
            float sv = sc_s[tid];
            float m = sv;
            for (int off = 1; off < 32; off <<= 1) m = fmaxf(m, __shfl_xor(m, off));
            float e = expf(sv - m);
            float ssum = e;
            for (int off = 1; off < 32; off <<= 1) ssum += __shfl_xor(ssum, off);
            float prob = e / ssum;
            atomicAdd(&a.mp_all[t * 32 + tid], prob);
            float bs = sv; int bi = tid;
            for (int off = 1; off < 32; off <<= 1) {
                float os = __shfl_xor(bs, off);
                int   oi = __shfl_xor(bi, off);
                if (os > bs || (os == bs && oi < bi)) { bs = os; bi = oi; }
            }
            if (tid == 0) {
                int next = nbr_s[bi];
                a.pos[w] = next;
                if (t == T_ - 1) a.out_pos[w] = (float)next;
                atomicAdd(&a.out_co[(size_t)pold * N_ + next], 1.0f);
                atomicAdd(&a.out_vc[next], 1.0f);
            }
        }
        atomicAdd(&a.out_s[((size_t)b * N_ + pold) * DS_ + tid], csum);
        float wn = a.out_ws[(size_t)w * DS_ + tid] + csum;
        a.out_ws[(size_t)w * DS_ + tid] = wn;
        atomicAdd(&a.out_motor[((size_t)b * T_ + t) * DS_ + tid], wn * (1.0f / H_));
    }
}

__global__ __launch_bounds__(256) void final_kernel(KArgs a)
{
    int tid = threadIdx.x;
    float v = a.mp_all[tid] * (1.0f / 256.f);
    v = v * v;
    for (int off = 32; off > 0; off >>= 1) v += __shfl_down(v, off);
    __shared__ float red[4];
    if ((tid & 63) == 0) red[tid >> 6] = v;
    __syncthreads();
    if (tid == 0) a.out_lb[0] = (float)K_ * (red[0] + red[1] + red[2] + red[3]);
}

// ---------------- launch ----------------

extern "C" void kernel_launch(void* const* d_in, const int* in_sizes, int n_in,
                              void* d_out, int out_size, void* d_ws, size_t ws_size,
                              hipStream_t stream)
{
    KArgs a;
    a.s_in    = (const float*)d_in[0];
    a.node_id = (const float*)d_in[1];
    a.ws_in   = (const float*)d_in[2];
    a.token   = (const float*)d_in[3];
    a.norm_w  = (const float*)d_in[4];
    a.W1  = (const float*)d_in[5];
    a.b1  = (const float*)d_in[6];
    a.W2  = (const float*)d_in[7];
    a.b2  = (const float*)d_in[8];
    a.qw1 = (const float*)d_in[9];
    a.qb1 = (const float*)d_in[10];
    a.qw2 = (const float*)d_in[11];
    a.qb2 = (const float*)d_in[12];
    a.kw1 = (const float*)d_in[13];
    a.kb1 = (const float*)d_in[14];
    a.kw2 = (const float*)d_in[15];
    a.kb2 = (const float*)d_in[16];
    a.walker_pos = (const int*)d_in[17];
    a.plane_idx  = (const int*)d_in[18];
    a.neighbors  = (const int*)d_in[19];

    float* out = (float*)d_out;
    a.out_motor = out;                               // 32768
    a.out_s     = a.out_motor + 32768;               // 16777216
    a.out_pos   = a.out_s + (size_t)16777216;        // 256
    a.out_ws    = a.out_pos + 256;                   // 65536
    a.out_co    = a.out_ws + 65536;                  // 16777216
    a.out_vc    = a.out_co + (size_t)16777216;       // 4096
    a.out_lb    = a.out_vc + 4096;                   // 1

    float* ws = (float*)d_ws;
    a.keys   = ws;                                   // 1,048,576
    a.qw1T   = a.keys + 1048576;                     // 458,752
    a.qw2T   = a.qw1T + 458752;                      // 131,072
    a.h1p    = a.qw2T + 131072;                      // 2,097,152 (4 partials)
    a.kh     = a.h1p;                                // alias (setup only)
    a.q1p    = a.h1p + 2097152;                      // 524,288 (4 partials, [j][w])
    a.c2p    = a.q1p + 524288;                       // 1,048,576 (transposed, 8)
    a.q2p    = a.c2p + 1048576;                      // 524,288 (8 partials, [w][col])
    a.mp_all = a.q2p + 524288;                       // 256
    a.pos         = (int*)(a.mp_all + 256);          // 256
    a.plane_order = a.pos + 256;                     // 2048
    a.chunk_plane = a.plane_order + 2048;            // 16
    a.chunk_rows  = a.chunk_plane + 16;              // 512
    a.slot_of     = a.chunk_rows + 512;              // 256
    a.nchunks     = a.slot_of + 256;                 // 1
    a.done        = a.nchunks + 1;                   // 8

    // zero outputs via runtime fill path (~6.9 TB/s measured on this chip)
    hipMemsetAsync(a.out_motor, 0, 32768 * sizeof(float), stream);
    hipMemsetAsync(a.out_co, 0, (size_t)(16777216 + 4096 + 1) * sizeof(float), stream);

    setup1_kernel<<<1024 + 1 + 576 + 2048, 256, 0, stream>>>(a);
    setup2_kernel<<<512, 256, 0, stream>>>(a);
    for (int t = 0; t < T_; ++t) {
        l1_kernel<<<256 + 1024, 256, 0, stream>>>(a, t);
        l2fs_kernel<<<1024, 256, 0, stream>>>(a, t);
    }
    final_kernel<<<1, 256, 0, stream>>>(a);
}

// Round 16
// 455.616 us; speedup vs baseline: 3.3551x; 3.3551x over previous
//
#include <hip/hip_runtime.h>
#include <math.h>

#define B_    16
#define H_    16
#define N_    4096
#define T_    8
#define DS_   256
#define DID_  128
#define L_    8
#define K_    32
#define DHID_ 1024
#define DSTEER_ 896
#define QH_   512
#define QO_   256
#define NW_   256   // B*H walkers
#define SLOTS_ 512  // chunk-slot space: 16 chunks x 32 slots
#define BSLD_ 36    // LDS B-tile row pad (conflict-free b128 reads)
#define SCORE_SCALE 0.022097086912079608f  // 1/(8*sqrt(32))

struct KArgs {
    const float *s_in, *node_id, *ws_in, *token, *norm_w;
    const float *W1, *b1, *W2, *b2;
    const float *qw1, *qb1, *qw2, *qb2, *kw1, *kb1, *kw2, *kb2;
    const int *walker_pos, *plane_idx, *neighbors;
    float *out_motor, *out_s, *out_pos, *out_ws, *out_co, *out_vc, *out_lb;
    float *keys, *qw1T, *qw2T, *h1p, *q1p, *c2p, *q2p, *mp_all;
    int *pos, *plane_order, *chunk_plane, *chunk_rows, *slot_of, *nchunks;
};

__device__ __forceinline__ float gelu_exact(float x) {
    return 0.5f * x * (1.0f + erff(x * 0.70710678118654752f));
}

#define FMA4(c, b, a) { c.x = fmaf(b.x, (a), c.x); c.y = fmaf(b.y, (a), c.y); \
                        c.z = fmaf(b.z, (a), c.z); c.w = fmaf(b.w, (a), c.w); }

__device__ __forceinline__ void gelu4(float4& v) {
    v.x = gelu_exact(v.x); v.y = gelu_exact(v.y);
    v.z = gelu_exact(v.z); v.w = gelu_exact(v.w);
}

// 2-row x 4-col register tile; A from global, B in LDS (row stride ldb).
__device__ __forceinline__ void rgemm_inner(
    const float* __restrict__ a0, const float* __restrict__ a1,
    const float* bp, int ldb, int K,
    float4& c0, float4& c1)
{
    for (int k = 0; k < K; k += 8) {
        const float4 a0l = *reinterpret_cast<const float4*>(a0 + k);
        const float4 a0h = *reinterpret_cast<const float4*>(a0 + k + 4);
        const float4 a1l = *reinterpret_cast<const float4*>(a1 + k);
        const float4 a1h = *reinterpret_cast<const float4*>(a1 + k + 4);
        const float* b8 = bp + (size_t)k * ldb;
#define KSTEP(o, av0, av1) { float4 bv = *reinterpret_cast<const float4*>(b8 + (size_t)(o) * ldb); \
                             FMA4(c0, bv, av0); FMA4(c1, bv, av1); }
        KSTEP(0, a0l.x, a1l.x)
        KSTEP(1, a0l.y, a1l.y)
        KSTEP(2, a0l.z, a1l.z)
        KSTEP(3, a0l.w, a1l.w)
        KSTEP(4, a0h.x, a1h.x)
        KSTEP(5, a0h.y, a1h.y)
        KSTEP(6, a0h.z, a1h.z)
        KSTEP(7, a0h.w, a1h.w)
#undef KSTEP
    }
}

// ---- setup1: fused keys (0..511) + tables (512) + qw1T/qw2T transpose
//      (513..1088) + s/ws copy (1089..3136) ---------------------------------

__global__ __launch_bounds__(256) void setup1_kernel(KArgs a)
{
    int bid = blockIdx.x, tid = threadIdx.x;
    if (bid < 512) {
        // keys = mlp2(node_id), both layers fused; 8 nodes per block.
        // Accumulation order matches r14 (sequential fmaf over k) so keys
        // are bitwise-identical to the two-kernel version.
        __shared__ float id_s[8 * 128];      // 4 KB
        __shared__ float hs[8 * 512];        // 16 KB
        int n0 = bid * 8;
        {   // stage node_id rows (256 float4s)
            int r = tid >> 5, d4 = (tid & 31) << 2;
            *reinterpret_cast<float4*>(id_s + r * 128 + d4) =
                *reinterpret_cast<const float4*>(a.node_id + (size_t)(n0 + r) * DID_ + d4);
        }
        __syncthreads();
        {   // layer 1: each thread 2 j-cols x 8 nodes
            int j0 = tid * 2;
            float acc0[8], acc1[8];
#pragma unroll
            for (int n = 0; n < 8; ++n) { acc0[n] = 0.f; acc1[n] = 0.f; }
            for (int d = 0; d < 128; ++d) {
                float2 wv = *reinterpret_cast<const float2*>(a.kw1 + (size_t)d * QH_ + j0);
#pragma unroll
                for (int n = 0; n < 8; ++n) {
                    float idv = id_s[n * 128 + d];
                    acc0[n] = fmaf(idv, wv.x, acc0[n]);
                    acc1[n] = fmaf(idv, wv.y, acc1[n]);
                }
            }
            float b0 = a.kb1[j0], b1v = a.kb1[j0 + 1];
#pragma unroll
            for (int n = 0; n < 8; ++n) {
                hs[n * 512 + j0]     = gelu_exact(acc0[n] + b0);
                hs[n * 512 + j0 + 1] = gelu_exact(acc1[n] + b1v);
            }
        }
        __syncthreads();
        {   // layer 2: each thread 1 o-col x 8 nodes
            int o = tid;
            float acc[8];
#pragma unroll
            for (int n = 0; n < 8; ++n) acc[n] = 0.f;
            for (int h = 0; h < 512; ++h) {
                float wv = a.kw2[(size_t)h * QO_ + o];
#pragma unroll
                for (int n = 0; n < 8; ++n)
                    acc[n] = fmaf(hs[n * 512 + h], wv, acc[n]);
            }
            float bo = a.kb2[o];
#pragma unroll
            for (int n = 0; n < 8; ++n)
                a.keys[(size_t)(n0 + n) * QO_ + o] = acc[n] + bo;
        }
    } else if (bid == 512) {
        a.pos[tid] = a.walker_pos[tid];
        a.mp_all[tid] = 0.f;
        __shared__ int cnt_s[8];
        __shared__ int cplane_s[16], cbase_s[16];
        __shared__ int nch_s;
        int wave = tid >> 6, lane = tid & 63;
        for (int pp = wave; pp < 8; pp += 4) {
            int base = 0;
            for (int c0 = 0; c0 < NW_; c0 += 64) {
                int w = c0 + lane;
                bool hit = (a.plane_idx[w] == pp);
                unsigned long long mask = __ballot(hit);
                if (hit) {
                    int rank = __popcll(mask & ((1ull << lane) - 1ull));
                    a.plane_order[pp * NW_ + base + rank] = w;
                }
                base += __popcll(mask);
            }
            if (lane == 0) cnt_s[pp] = base;
        }
        __syncthreads();
        if (tid == 0) {
            int nc = 0;
            for (int p = 0; p < 8; ++p)
                for (int s0 = 0; s0 < cnt_s[p]; s0 += 32) {
                    cplane_s[nc] = p; cbase_s[nc] = s0; ++nc;
                }
            *a.nchunks = nc;
            nch_s = nc;
        }
        __syncthreads();
        int nc = nch_s;
        for (int idx = tid; idx < 512; idx += 256) {
            int c = idx >> 5, i = idx & 31;
            int v = -1;
            if (c < nc) {
                int p = cplane_s[c];
                int r = cbase_s[c] + i;
                if (r < cnt_s[p]) v = a.plane_order[p * NW_ + r];
            }
            a.chunk_rows[c * 32 + i] = v;
            if (v >= 0) a.slot_of[v] = c * 32 + i;
            if (i == 0) a.chunk_plane[c] = (c < nc) ? cplane_s[c] : 0;
        }
    } else if (bid < 1089) {
        // weight transposes via 32x32 LDS tiles
        __shared__ float ts[32][33];
        int u = bid - 513;
        const float* src; float* dst; int srcld, dstld, td, tj;
        if (u < 448) {              // qw1 [896][512] -> qw1T [512][896]
            src = a.qw1; dst = a.qw1T; srcld = QH_; dstld = DSTEER_;
            td = u >> 4; tj = u & 15;
        } else {                    // qw2 [512][256] -> qw2T [256][512]
            u -= 448;               // 128 blocks
            src = a.qw2; dst = a.qw2T; srcld = QO_; dstld = QH_;
            td = u >> 3; tj = u & 7;
        }
#pragma unroll
        for (int i = 0; i < 4; ++i) {
            int e = tid + i * 256;
            int r = e >> 5, cc = e & 31;
            ts[r][cc] = src[(size_t)(td * 32 + r) * srcld + tj * 32 + cc];
        }
        __syncthreads();
#pragma unroll
        for (int i = 0; i < 4; ++i) {
            int e = tid + i * 256;
            int r = e >> 5, cc = e & 31;
            dst[(size_t)(tj * 32 + r) * dstld + td * 32 + cc] = ts[cc][r];
        }
    } else {
        // s / ws restore copy
        int gid = (bid - 1089) * 256 + tid, stride = 2048 * 256;
        float4* s4o = reinterpret_cast<float4*>(a.out_s);
        const float4* s4i = reinterpret_cast<const float4*>(a.s_in);
        for (int i = gid; i < 4194304; i += stride) s4o[i] = s4i[i];
        float4* w4o = reinterpret_cast<float4*>(a.out_ws);
        const float4* w4i = reinterpret_cast<const float4*>(a.ws_in);
        for (int i = gid; i < 16384; i += stride) w4o[i] = w4i[i];
    }
}

// ---------------- layer1 with fused steer staging (r14 proven) ----------------

__global__ __launch_bounds__(256) void l1_kernel(KArgs a, int t)
{
    __shared__ float bs[224 * BSLD_];        // 32.25 KB
    __shared__ float rms_s[32];
    __shared__ int w_s[32], pos_s[32];
    int bid = blockIdx.x, tid = threadIdx.x;
    int kp, jt, c = -1, p = 0, wt = 0, isQ;
    if (bid < 256) {
        isQ = 1; kp = bid & 3;
        int tile = bid >> 2;                 // 64: wt(8) x jt(8)
        wt = tile >> 3; jt = tile & 7;
    } else {
        isQ = 0;
        int b2 = bid - 256; kp = b2 & 3;
        int tile = b2 >> 2;                  // 256: c(16) x jt(16)
        c = tile >> 4; jt = tile & 15;
        if (c >= *a.nchunks) return;
        p = a.chunk_plane[c];
    }
    int g = tid >> 3, l8 = tid & 7;          // g: walker column, l8: k-chunk
    if (l8 == 0) {
        int w = isQ ? (wt * 32 + g) : a.chunk_rows[c * 32 + g];
        w_s[g] = w;
        pos_s[g] = (w >= 0) ? a.pos[w] : 0;
    }
    __syncthreads();
    if (kp < 2) {                            // rms only needed when slice hits s_n
        int w = w_s[g];
        float ssum = 0.f;
        if (w >= 0) {
            const float* sr = a.out_s + ((size_t)(w >> 4) * N_ + pos_s[g]) * DS_ + l8 * 32;
#pragma unroll
            for (int i = 0; i < 8; ++i) {
                float4 v = *reinterpret_cast<const float4*>(sr + i * 4);
                ssum += v.x * v.x + v.y * v.y + v.z * v.z + v.w * v.w;
            }
        }
        ssum += __shfl_xor(ssum, 1);
        ssum += __shfl_xor(ssum, 2);
        ssum += __shfl_xor(ssum, 4);
        if (l8 == 0) rms_s[g] = rsqrtf(ssum * (1.0f / DS_) + 1e-6f);
    }
    __syncthreads();
    {   // stage B: column g, elems kk = l8*28 .. +28
        int w = w_s[g];
        int b = (w >= 0) ? (w >> 4) : 0;
        int pp = pos_s[g];
        float rr = (kp < 2) ? rms_s[g] : 0.f;
#pragma unroll
        for (int i = 0; i < 7; ++i) {
            int kk = l8 * 28 + i * 4;
            int d4 = kp * 224 + kk;
            float4 v = make_float4(0.f, 0.f, 0.f, 0.f);
            if (w >= 0) {
                if (d4 < 256) {
                    float4 sv = *reinterpret_cast<const float4*>(
                        a.out_s + ((size_t)b * N_ + pp) * DS_ + d4);
                    float4 nv = *reinterpret_cast<const float4*>(a.norm_w + d4);
                    v.x = sv.x * rr * nv.x; v.y = sv.y * rr * nv.y;
                    v.z = sv.z * rr * nv.z; v.w = sv.w * rr * nv.w;
                } else if (d4 < 384) {
                    v = *reinterpret_cast<const float4*>(
                        a.node_id + (size_t)pp * DID_ + (d4 - 256));
                } else if (d4 < 640) {
                    v = *reinterpret_cast<const float4*>(
                        a.out_ws + (size_t)w * DS_ + (d4 - 384));
                } else {
                    v = *reinterpret_cast<const float4*>(
                        a.token + ((size_t)b * T_ + t) * DS_ + (d4 - 640));
                }
            }
            bs[(kk + 0) * BSLD_ + g] = v.x;
            bs[(kk + 1) * BSLD_ + g] = v.y;
            bs[(kk + 2) * BSLD_ + g] = v.z;
            bs[(kk + 3) * BSLD_ + g] = v.w;
        }
    }
    __syncthreads();
    int tr = tid >> 3, tc = tid & 7;
    float4 c0 = {0.f,0.f,0.f,0.f}, c1 = {0.f,0.f,0.f,0.f};
    if (isQ) {
        int j = jt * 64 + tr * 2;
        const float* a0 = a.qw1T + (size_t)j * DSTEER_ + kp * 224;
        rgemm_inner(a0, a0 + DSTEER_, bs + tc * 4, BSLD_, 224, c0, c1);
        float* o = a.q1p + (size_t)kp * 131072;  // [512 j][256 w]
        int w4 = wt * 32 + tc * 4;
        *reinterpret_cast<float4*>(o + (size_t)j * NW_ + w4) = c0;
        *reinterpret_cast<float4*>(o + (size_t)(j + 1) * NW_ + w4) = c1;
    } else {
        int J = jt * 64 + tr * 2;
        const float* a0 = a.W1 + ((size_t)p * DHID_ + J) * DSTEER_ + kp * 224;
        rgemm_inner(a0, a0 + DSTEER_, bs + tc * 4, BSLD_, 224, c0, c1);
        float* o = a.h1p + (size_t)kp * 524288;  // [1024 J][512 slots]
        int slot = c * 32 + tc * 4;
        *reinterpret_cast<float4*>(o + (size_t)J * SLOTS_ + slot) = c0;
        *reinterpret_cast<float4*>(o + (size_t)(J + 1) * SLOTS_ + slot) = c1;
    }
}

// ---------------- layer2 fused (r14 proven) ----------------

__global__ __launch_bounds__(256) void l2f_kernel(KArgs a)
{
    __shared__ float smem[4224];             // 16.5 KB
    int bid = blockIdx.x, tid = threadIdx.x;
    if (bid < 256) {
        int kp = bid & 7, tile = bid >> 3;   // 32: colt(4) x wt(8)
        int colt = tile >> 3, wt = tile & 7;
#pragma unroll
        for (int i = 0; i < 8; ++i) {
            int idx = tid + i * 256;         // 2048
            int hh = idx >> 5, wl = idx & 31;
            size_t off = (size_t)(kp * 64 + hh) * NW_ + wt * 32 + wl;
            float acc = a.qb1[kp * 64 + hh];
#pragma unroll
            for (int p4 = 0; p4 < 4; ++p4) acc += a.q1p[(size_t)p4 * 131072 + off];
            smem[hh * 32 + wl] = gelu_exact(acc);
        }
        __syncthreads();
        int tr = tid >> 3, tc = tid & 7;
        int col = colt * 64 + tr * 2;
        const float* a0 = a.qw2T + (size_t)col * QH_ + kp * 64;
        float4 c0 = {0.f,0.f,0.f,0.f}, c1 = {0.f,0.f,0.f,0.f};
        rgemm_inner(a0, a0 + QH_, smem + tc * 4, 32, 64, c0, c1);
        __syncthreads();
        int cl = tr * 2;
        smem[(tc*4+0)*66 + cl]     = c0.x;
        smem[(tc*4+1)*66 + cl]     = c0.y;
        smem[(tc*4+2)*66 + cl]     = c0.z;
        smem[(tc*4+3)*66 + cl]     = c0.w;
        smem[(tc*4+0)*66 + cl + 1] = c1.x;
        smem[(tc*4+1)*66 + cl + 1] = c1.y;
        smem[(tc*4+2)*66 + cl + 1] = c1.z;
        smem[(tc*4+3)*66 + cl + 1] = c1.w;
        __syncthreads();
        float* o = a.q2p + (size_t)kp * 65536;   // [256 w][256 col]
#pragma unroll
        for (int i = 0; i < 2; ++i) {
            int f4i = tid + i * 256;
            int wl = f4i >> 4, j4 = (f4i & 15) << 2;
            float4 v;
            v.x = smem[wl * 66 + j4 + 0];
            v.y = smem[wl * 66 + j4 + 1];
            v.z = smem[wl * 66 + j4 + 2];
            v.w = smem[wl * 66 + j4 + 3];
            *reinterpret_cast<float4*>(o + (size_t)(wt * 32 + wl) * QO_ + colt * 64 + j4) = v;
        }
    } else {
        int b2i = bid - 256;
        int kp = b2i & 7, tile = b2i >> 3;
        int c = tile >> 2, jt = tile & 3;
        if (c >= *a.nchunks) return;
        int p = a.chunk_plane[c];
        int tr = tid >> 3, tc = tid & 7;
        int J = jt * 64 + tr * 2;
        float4 c0 = {0.f,0.f,0.f,0.f}, c1 = {0.f,0.f,0.f,0.f};
#pragma unroll
        for (int i = 0; i < 4; ++i) {
            int idx = tid + i * 256;         // 1024
            int kk = idx >> 3, s4 = (idx & 7) << 2;
            int kq = kp * 128 + kk;
            size_t off = (size_t)kq * SLOTS_ + c * 32 + s4;
            float bj = a.b1[p * DHID_ + kq];
            float4 acc = {bj, bj, bj, bj};
#pragma unroll
            for (int p4 = 0; p4 < 4; ++p4) {
                float4 v = *reinterpret_cast<const float4*>(a.h1p + (size_t)p4 * 524288 + off);
                acc.x += v.x; acc.y += v.y; acc.z += v.z; acc.w += v.w;
            }
            gelu4(acc);
            *reinterpret_cast<float4*>(smem + kk * 32 + s4) = acc;
        }
        __syncthreads();
        const float* a0 = a.W2 + ((size_t)p * DS_ + J) * DHID_ + kp * 128;
        rgemm_inner(a0, a0 + DHID_, smem + tc * 4, 32, 128, c0, c1);
        __syncthreads();
        int jl = tr * 2;
        smem[(tc*4+0)*66 + jl]     = c0.x;
        smem[(tc*4+1)*66 + jl]     = c0.y;
        smem[(tc*4+2)*66 + jl]     = c0.z;
        smem[(tc*4+3)*66 + jl]     = c0.w;
        smem[(tc*4+0)*66 + jl + 1] = c1.x;
        smem[(tc*4+1)*66 + jl + 1] = c1.y;
        smem[(tc*4+2)*66 + jl + 1] = c1.z;
        smem[(tc*4+3)*66 + jl + 1] = c1.w;
        __syncthreads();
        float* o = a.c2p + (size_t)kp * 131072;  // [512 slot][256 J]
#pragma unroll
        for (int i = 0; i < 2; ++i) {
            int f4i = tid + i * 256;
            int sl = f4i >> 4, j4 = (f4i & 15) << 2;
            float4 v;
            v.x = smem[sl * 66 + j4 + 0];
            v.y = smem[sl * 66 + j4 + 1];
            v.z = smem[sl * 66 + j4 + 2];
            v.w = smem[sl * 66 + j4 + 3];
            *reinterpret_cast<float4*>(o + (size_t)(c * 32 + sl) * 256 + jt * 64 + j4) = v;
        }
    }
}

// ---------------- score (r14 proven) ----------------

__global__ __launch_bounds__(256) void score_kernel(KArgs a, int t)
{
    int w = blockIdx.x;
    int b = w >> 4;
    int tid = threadIdx.x;
    int pold = a.pos[w];
    int slot = a.slot_of[w];
    __shared__ float qv_s[256];
    __shared__ int nbr_s[32];
    __shared__ float part_s[8][32];
    __shared__ float sc_s[32];
    if (tid < 32) nbr_s[tid] = a.neighbors[(size_t)pold * K_ + tid];
    float qsum = a.qb2[tid];
#pragma unroll
    for (int kp = 0; kp < 8; ++kp) qsum += a.q2p[(size_t)kp * 65536 + (size_t)w * QO_ + tid];
    qv_s[tid] = qsum;
    float csum = a.b2[a.chunk_plane[slot >> 5] * DS_ + tid];
#pragma unroll
    for (int kp = 0; kp < 8; ++kp) csum += a.c2p[(size_t)kp * 131072 + (size_t)slot * 256 + tid];
    __syncthreads();
    int k = tid & 31, part = tid >> 5;
    int nk = nbr_s[k];
    const float* kp_ = a.keys + (size_t)nk * 256 + part * 32;
    const float* qp = qv_s + part * 32;
    float acc = 0.f;
#pragma unroll
    for (int i = 0; i < 32; i += 4) {
        float4 kv = *reinterpret_cast<const float4*>(kp_ + i);
        acc += kv.x * qp[i] + kv.y * qp[i+1] + kv.z * qp[i+2] + kv.w * qp[i+3];
    }
    part_s[part][k] = acc;
    __syncthreads();
    if (tid < 32) {
        float s = 0.f;
#pragma unroll
        for (int p8 = 0; p8 < 8; ++p8) s += part_s[p8][tid];
        sc_s[tid] = s * SCORE_SCALE;
    }
    __syncthreads();
    if (tid < 32) {
        float sv = sc_s[tid];
        float m = sv;
        for (int off = 1; off < 32; off <<= 1) m = fmaxf(m, __shfl_xor(m, off));
        float e = expf(sv - m);
        float ssum = e;
        for (int off = 1; off < 32; off <<= 1) ssum += __shfl_xor(ssum, off);
        float prob = e / ssum;
        atomicAdd(&a.mp_all[t * 32 + tid], prob);
        float bs = sv; int bi = tid;
        for (int off = 1; off < 32; off <<= 1) {
            float os = __shfl_xor(bs, off);
            int   oi = __shfl_xor(bi, off);
            if (os > bs || (os == bs && oi < bi)) { bs = os; bi = oi; }
        }
        if (tid == 0) {
            int next = nbr_s[bi];
            a.pos[w] = next;
            if (t == T_ - 1) a.out_pos[w] = (float)next;
            atomicAdd(&a.out_co[(size_t)pold * N_ + next], 1.0f);
            atomicAdd(&a.out_vc[next], 1.0f);
        }
    }
    atomicAdd(&a.out_s[((size_t)b * N_ + pold) * DS_ + tid], csum);
    float wn = a.out_ws[(size_t)w * DS_ + tid] + csum;
    a.out_ws[(size_t)w * DS_ + tid] = wn;
    atomicAdd(&a.out_motor[((size_t)b * T_ + t) * DS_ + tid], wn * (1.0f / H_));
}

__global__ __launch_bounds__(256) void final_kernel(KArgs a)
{
    int tid = threadIdx.x;
    float v = a.mp_all[tid] * (1.0f / 256.f);
    v = v * v;
    for (int off = 32; off > 0; off >>= 1) v += __shfl_down(v, off);
    __shared__ float red[4];
    if ((tid & 63) == 0) red[tid >> 6] = v;
    __syncthreads();
    if (tid == 0) a.out_lb[0] = (float)K_ * (red[0] + red[1] + red[2] + red[3]);
}

// ---------------- launch ----------------

extern "C" void kernel_launch(void* const* d_in, const int* in_sizes, int n_in,
                              void* d_out, int out_size, void* d_ws, size_t ws_size,
                              hipStream_t stream)
{
    KArgs a;
    a.s_in    = (const float*)d_in[0];
    a.node_id = (const float*)d_in[1];
    a.ws_in   = (const float*)d_in[2];
    a.token   = (const float*)d_in[3];
    a.norm_w  = (const float*)d_in[4];
    a.W1  = (const float*)d_in[5];
    a.b1  = (const float*)d_in[6];
    a.W2  = (const float*)d_in[7];
    a.b2  = (const float*)d_in[8];
    a.qw1 = (const float*)d_in[9];
    a.qb1 = (const float*)d_in[10];
    a.qw2 = (const float*)d_in[11];
    a.qb2 = (const float*)d_in[12];
    a.kw1 = (const float*)d_in[13];
    a.kb1 = (const float*)d_in[14];
    a.kw2 = (const float*)d_in[15];
    a.kb2 = (const float*)d_in[16];
    a.walker_pos = (const int*)d_in[17];
    a.plane_idx  = (const int*)d_in[18];
    a.neighbors  = (const int*)d_in[19];

    float* out = (float*)d_out;
    a.out_motor = out;                               // 32768
    a.out_s     = a.out_motor + 32768;               // 16777216
    a.out_pos   = a.out_s + (size_t)16777216;        // 256
    a.out_ws    = a.out_pos + 256;                   // 65536
    a.out_co    = a.out_ws + 65536;                  // 16777216
    a.out_vc    = a.out_co + (size_t)16777216;       // 4096
    a.out_lb    = a.out_vc + 4096;                   // 1

    float* ws = (float*)d_ws;
    a.keys   = ws;                                   // 1,048,576
    a.qw1T   = a.keys + 1048576;                     // 458,752
    a.qw2T   = a.qw1T + 458752;                      // 131,072
    a.h1p    = a.qw2T + 131072;                      // 2,097,152 (4 partials)
    a.q1p    = a.h1p + 2097152;                      // 524,288 (4 partials, [j][w])
    a.c2p    = a.q1p + 524288;                       // 1,048,576 (transposed, 8)
    a.q2p    = a.c2p + 1048576;                      // 524,288 (8 partials, [w][col])
    a.mp_all = a.q2p + 524288;                       // 256
    a.pos         = (int*)(a.mp_all + 256);          // 256
    a.plane_order = a.pos + 256;                     // 2048
    a.chunk_plane = a.plane_order + 2048;            // 16
    a.chunk_rows  = a.chunk_plane + 16;              // 512
    a.slot_of     = a.chunk_rows + 512;              // 256
    a.nchunks     = a.slot_of + 256;                 // 1

    // zero outputs via runtime fill path (~6.9 TB/s measured on this chip)
    hipMemsetAsync(a.out_motor, 0, 32768 * sizeof(float), stream);
    hipMemsetAsync(a.out_co, 0, (size_t)(16777216 + 4096 + 1) * sizeof(float), stream);

    setup1_kernel<<<512 + 1 + 576 + 2048, 256, 0, stream>>>(a);
    for (int t = 0; t < T_; ++t) {
        l1_kernel<<<256 + 1024, 256, 0, stream>>>(a, t);
        l2f_kernel<<<768, 256, 0, stream>>>(a);
        score_kernel<<<256, 256, 0, stream>>>(a, t);
    }
    final_kernel<<<1, 256, 0, stream>>>(a);
}